// Round 9
// baseline (599.565 us; speedup 1.0000x reference)
//
#include <hip/hip_runtime.h>
#include <cstdint>
#include <cstddef>

// Problem constants
#define B_   4
#define S_   1024
#define D_   1024
#define H_   16
#define DH_  64
#define DFF_ 4096
#define M_   (B_ * S_)   // 4096 rows for all linears

typedef __bf16 bf16x8 __attribute__((ext_vector_type(8)));
typedef float  f32x4  __attribute__((ext_vector_type(4)));

__device__ __forceinline__ unsigned short f2bf(float f) {
  unsigned int u = __float_as_uint(f);
  u = (u + 0x7fffu + ((u >> 16) & 1u)) >> 16;   // round-to-nearest-even
  return (unsigned short)u;
}

__device__ __forceinline__ float bf2f(unsigned short h) {
  return __uint_as_float(((unsigned int)h) << 16);
}

// async global->LDS: lds dest is WAVE-UNIFORM base; HW adds lane*16 (m104)
__device__ __forceinline__ void gload_lds16(const void* g, void* l) {
  __builtin_amdgcn_global_load_lds((const __attribute__((address_space(1))) void*)g,
                                   (__attribute__((address_space(3))) void*)l, 16, 0, 0);
}

// ---------------------------------------------------------------------------
// Fused f32 -> bf16 conversion (13 tensors: 10 weights + 3 inputs)
// ---------------------------------------------------------------------------
#define NCVT 16
struct CvtB { const float* s[NCVT]; unsigned short* d[NCVT]; int n[NCVT]; };

__global__ __launch_bounds__(256)
void cvt_k(CvtB cb) {
  const int z = blockIdx.y;
  const float* __restrict__ s = cb.s[z];
  unsigned short* __restrict__ d = cb.d[z];
  const int n = cb.n[z];
  const int stride = gridDim.x * 256 * 4;
  for (int i = (blockIdx.x * 256 + threadIdx.x) * 4; i < n; i += stride) {
    const float4 v = *(const float4*)(s + i);
    const unsigned int a = (unsigned int)f2bf(v.x) | ((unsigned int)f2bf(v.y) << 16);
    const unsigned int b = (unsigned int)f2bf(v.z) | ((unsigned int)f2bf(v.w) << 16);
    *(uint2*)(d + i) = make_uint2(a, b);
  }
}

// ---------------------------------------------------------------------------
// Weight transpose f32 -> bf16: T[n][k] = S[k][n], 1024x1024, z-batched x3.
// Coalesced reads (lanes span a source row); 16B writes per thread.
// grid (32, 16, 3) x 256.
// ---------------------------------------------------------------------------
struct WtB { const float* s[3]; unsigned short* d[3]; };

__global__ __launch_bounds__(256)
void wtrans_k(WtB wb) {
  const int z = blockIdx.z;
  const float* __restrict__ S = wb.s[z];
  unsigned short* __restrict__ T = wb.d[z];
  const int t = threadIdx.x;
  const int dcol = blockIdx.y * 64 + (t & 63);     // src col = dst row
  const int r0   = blockIdx.x * 32 + (t >> 6) * 8; // src rows
  unsigned short tmp[8];
#pragma unroll
  for (int i = 0; i < 8; ++i)
    tmp[i] = f2bf(S[(size_t)(r0 + i) * 1024 + dcol]);
  *(uint4*)(T + (size_t)dcol * 1024 + r0) = *(const uint4*)tmp;
}

// ---------------------------------------------------------------------------
// Composed bias: o[n] = sum_k Wp[n][k]*be[k] + pb[n]  (all f32), z-batched x4.
// Wave-per-output: coalesced row reads, shfl reduce. grid (16, 4) x 256.
// ---------------------------------------------------------------------------
struct BcB { const float* w[4]; const float* eb[4]; const float* pb[4]; float* o[4]; };

__global__ __launch_bounds__(256)
void bcomp_k(BcB bb) {
  const int z = blockIdx.y;
  const float* __restrict__ Wp = bb.w[z];
  const float* __restrict__ be = bb.eb[z];
  const float* __restrict__ pb = bb.pb[z];
  float* __restrict__ o = bb.o[z];
  const int w = threadIdx.x >> 6, l = threadIdx.x & 63;
  for (int pass = 0; pass < 16; ++pass) {
    const int n = blockIdx.x * 64 + pass * 4 + w;
    const float* row = Wp + (size_t)n * 1024 + l * 16;
    float acc = 0.f;
#pragma unroll
    for (int i = 0; i < 4; ++i) {
      const float4 a = *(const float4*)(row + i * 4);
      const float4 b = *(const float4*)(be + l * 16 + i * 4);
      acc += a.x * b.x + a.y * b.y + a.z * b.z + a.w * b.w;
    }
    acc += __shfl_xor(acc, 1);  acc += __shfl_xor(acc, 2);
    acc += __shfl_xor(acc, 4);  acc += __shfl_xor(acc, 8);
    acc += __shfl_xor(acc, 16); acc += __shfl_xor(acc, 32);
    if (l == 0) o[n] = acc + pb[n];
  }
}

// ---------------------------------------------------------------------------
// Batched MFMA GEMM: Y[M,N] = A[M,K] @ W[N,K]^T (+ bias)  (bf16 in, f32 acc)
// 2-phase double-buffered (passing round-8 structure), XCD swizzle (m204).
// NB=1 skips the bias add (weight-composition GEMMs).
// ---------------------------------------------------------------------------
#define MAXB 6
struct GemmB {
  const unsigned short* A[MAXB];
  const unsigned short* W[MAXB];
  const float*          bias[MAXB];
  void*                 Y[MAXB];
};

template <int GELU, int OUTF32, int NB>
__global__ __launch_bounds__(256)
void mgemm(GemmB gb, int M, int N, int K) {
  __shared__ unsigned short sA0[128][32], sA1[128][32];   // 8 KB each
  __shared__ unsigned short sB0[128][32], sB1[128][32];

  const int z = blockIdx.z;
  const unsigned short* __restrict__ A = gb.A[z];
  const unsigned short* __restrict__ W = gb.W[z];
  const float* __restrict__ bias = gb.bias[z];

  const int t  = threadIdx.x;
  const int ln = t & 63;
  const int wv = t >> 6;
  const int wr = wv >> 1;
  const int wc = wv & 1;

  // bijective XCD swizzle (m204)
  const int gx   = gridDim.x;
  const int nwg  = gx * gridDim.y;
  const int orig = blockIdx.y * gx + blockIdx.x;
  const int q8   = nwg >> 3, r8 = nwg & 7;
  const int xcd  = orig & 7, idx = orig >> 3;
  const int wgid = (xcd < r8 ? xcd * (q8 + 1) : r8 * (q8 + 1) + (xcd - r8) * q8) + idx;
  const int m0 = (wgid / gx) * 128;
  const int n0 = (wgid % gx) * 128;

  const int srow  = ln >> 2;
  const int skoff = (ln & 3) << 3;

  f32x4 acc[4][4] = {};

  char* a0 = (char*)&sA0[0][0];  char* a1 = (char*)&sA1[0][0];
  char* b0 = (char*)&sB0[0][0];  char* b1 = (char*)&sB1[0][0];

  const int rsel = ln & 15;
  const int csel = (ln >> 4) << 4;

  auto stage = [&](int kt, char* dstA, char* dstB) {
    const int k0 = kt << 5;
#pragma unroll
    for (int i = 0; i < 2; ++i) {
      const int c = (wv << 1) | i;
      gload_lds16(A + (size_t)(m0 + (c << 4) + srow) * K + k0 + skoff, dstA + (c << 10));
      gload_lds16(W + (size_t)(n0 + (c << 4) + srow) * K + k0 + skoff, dstB + (c << 10));
    }
  };

  auto compute = [&](const char* srcA, const char* srcB) {
    bf16x8 av[4], bv[4];
#pragma unroll
    for (int m = 0; m < 4; ++m)
      av[m] = *(const bf16x8*)(srcA + (((wr << 6) + (m << 4) + rsel) << 6) + csel);
#pragma unroll
    for (int n = 0; n < 4; ++n)
      bv[n] = *(const bf16x8*)(srcB + (((wc << 6) + (n << 4) + rsel) << 6) + csel);
#pragma unroll
    for (int m = 0; m < 4; ++m)
#pragma unroll
      for (int n = 0; n < 4; ++n)
        acc[m][n] = __builtin_amdgcn_mfma_f32_16x16x32_bf16(av[m], bv[n], acc[m][n], 0, 0, 0);
  };

  const int NK = K >> 5;   // even for all our K
  stage(0, a0, b0);
  for (int kt = 0; kt < NK; kt += 2) {
    __syncthreads();
    stage(kt + 1, a1, b1);
    compute(a0, b0);
    __syncthreads();
    if (kt + 2 < NK) stage(kt + 2, a0, b0);
    compute(a1, b1);
  }

  const int rbase = m0 + (wr << 6) + ((ln >> 4) << 2);
  const int cb0   = n0 + (wc << 6) + (ln & 15);
#pragma unroll
  for (int m = 0; m < 4; ++m) {
#pragma unroll
    for (int n = 0; n < 4; ++n) {
      const int col = cb0 + (n << 4);
      const float bi = NB ? 0.f : bias[col];
#pragma unroll
      for (int j = 0; j < 4; ++j) {
        const int row = rbase + (m << 4) + j;
        float x = acc[m][n][j] + bi;
        if (GELU) x = 0.5f * x * (1.0f + erff(x * 0.70710678118654752f));
        if (OUTF32) ((float*)gb.Y[z])[(size_t)row * N + col] = x;
        else        ((unsigned short*)gb.Y[z])[(size_t)row * N + col] = f2bf(x);
      }
    }
  }
}

// ---------------------------------------------------------------------------
// Per-head V transpose: V[b*S+kv][h*64+d] -> Vt[bh][d][kv]
// ---------------------------------------------------------------------------
__global__ __launch_bounds__(256)
void vtrans_k(const unsigned short* __restrict__ V, unsigned short* __restrict__ Vt) {
  const int t   = threadIdx.x;
  const int d   = t & 63;
  const int sub = t >> 6;
  const int bh  = blockIdx.y;
  const int b   = bh >> 4;
  const int col0 = (bh & 15) * DH_;
  const int kv0 = blockIdx.x * 32 + sub * 8;
  unsigned short tmp[8];
#pragma unroll
  for (int i = 0; i < 8; ++i)
    tmp[i] = V[((size_t)b * S_ + kv0 + i) * D_ + col0 + d];
  *(uint4*)(Vt + ((size_t)bh * DH_ + d) * S_ + kv0) = *(const uint4*)tmp;
}

// ---------------------------------------------------------------------------
// MFMA flash attention, round-9: double-buffered K/V (issue-before-compute,
// ONE barrier per kv-tile — same transform that took mgemm 112->77 us).
// Fragment layouts unchanged from the passing round-6/8 kernel.
// ---------------------------------------------------------------------------
__global__ __launch_bounds__(256)
void attn_mfma_k(const unsigned short* __restrict__ Q,
                 const unsigned short* __restrict__ K,
                 const unsigned short* __restrict__ Vt,
                 const unsigned short* __restrict__ addend,
                 unsigned short* __restrict__ O) {
  __shared__ unsigned short sQ[64 * 64];
  __shared__ unsigned short sK0[64 * 64], sK1[64 * 64];
  __shared__ unsigned short sV0[64 * 64], sV1[64 * 64];
  __shared__ unsigned short sP[4][16 * 72];

  const int t  = threadIdx.x;
  const int l  = t & 63;
  const int w  = t >> 6;
  const int bh = blockIdx.y;
  const int b  = bh >> 4;
  const size_t rowQ = (size_t)b * S_ + blockIdx.x * 64;
  const size_t rowK = (size_t)b * S_;
  const int col0 = (bh & 15) * DH_;

  const int lr8 = l >> 3;
  const int lsw = (l & 7) ^ lr8;

  auto stageKV = [&](int kt, char* dK, char* dV) {
#pragma unroll
    for (int i = 0; i < 2; ++i) {
      const int r = w * 16 + i * 8 + lr8;
      gload_lds16(K + (rowK + (size_t)kt * 64 + r) * D_ + col0 + lsw * 8, dK + w * 2048 + i * 1024);
      gload_lds16(Vt + ((size_t)bh * DH_ + r) * S_ + kt * 64 + lsw * 8, dV + w * 2048 + i * 1024);
    }
  };

#pragma unroll
  for (int i = 0; i < 2; ++i) {
    const int r = w * 16 + i * 8 + lr8;
    gload_lds16(Q + (rowQ + r) * D_ + col0 + lsw * 8, (char*)sQ + w * 2048 + i * 1024);
  }
  stageKV(0, (char*)sK0, (char*)sV0);
  __syncthreads();

  bf16x8 qa[2];
#pragma unroll
  for (int c = 0; c < 2; ++c)
    qa[c] = *(const bf16x8*)((char*)sQ + (w * 16 + (l & 15)) * 128 +
                             ((((c << 2) + (l >> 4)) ^ (l & 7)) << 4));

  f32x4 o[4] = {};
  float mrow[4] = {-1e30f, -1e30f, -1e30f, -1e30f};
  float lrow[4] = {0.f, 0.f, 0.f, 0.f};
  char* sPw = (char*)(sP[w]);

  auto tile = [&](const char* sKb, const char* sVb) {
    f32x4 s[4];
#pragma unroll
    for (int n = 0; n < 4; ++n) {
      f32x4 zz = {};
#pragma unroll
      for (int c = 0; c < 2; ++c) {
        const bf16x8 kb = *(const bf16x8*)(sKb + (n * 16 + (l & 15)) * 128 +
                              ((((c << 2) + (l >> 4)) ^ (l & 7)) << 4));
        zz = __builtin_amdgcn_mfma_f32_16x16x32_bf16(qa[c], kb, zz, 0, 0, 0);
      }
      s[n] = zz;
    }

#pragma unroll
    for (int j = 0; j < 4; ++j) {
      float rm = fmaxf(fmaxf(s[0][j], s[1][j]), fmaxf(s[2][j], s[3][j]));
      rm = fmaxf(rm, __shfl_xor(rm, 1));
      rm = fmaxf(rm, __shfl_xor(rm, 2));
      rm = fmaxf(rm, __shfl_xor(rm, 4));
      rm = fmaxf(rm, __shfl_xor(rm, 8));
      const float mn = fmaxf(mrow[j], rm * 0.125f);
      const float cr = __expf(mrow[j] - mn);
      mrow[j] = mn;
      float rs = 0.f;
#pragma unroll
      for (int n = 0; n < 4; ++n) {
        const float p = __expf(s[n][j] * 0.125f - mn);
        rs += p;
        ((unsigned short*)sPw)[((l >> 4) * 4 + j) * 72 + n * 16 + (l & 15)] = f2bf(p);
      }
      rs += __shfl_xor(rs, 1);
      rs += __shfl_xor(rs, 2);
      rs += __shfl_xor(rs, 4);
      rs += __shfl_xor(rs, 8);
      lrow[j] = lrow[j] * cr + rs;
#pragma unroll
      for (int n2 = 0; n2 < 4; ++n2) o[n2][j] *= cr;
    }

    bf16x8 pa[2];
#pragma unroll
    for (int kc = 0; kc < 2; ++kc)
      pa[kc] = *(const bf16x8*)(sPw + (l & 15) * 144 + kc * 64 + (l >> 4) * 16);
#pragma unroll
    for (int n2 = 0; n2 < 4; ++n2) {
#pragma unroll
      for (int kc = 0; kc < 2; ++kc) {
        const bf16x8 vb = *(const bf16x8*)(sVb + (n2 * 16 + (l & 15)) * 128 +
                               ((((kc << 2) + (l >> 4)) ^ (l & 7)) << 4));
        o[n2] = __builtin_amdgcn_mfma_f32_16x16x32_bf16(pa[kc], vb, o[n2], 0, 0, 0);
      }
    }
  };

  for (int kt = 0; kt < S_ / 64; kt += 2) {
    if (kt + 1 < S_ / 64) stageKV(kt + 1, (char*)sK1, (char*)sV1);
    tile((char*)sK0, (char*)sV0);
    __syncthreads();                 // buf1 ready; everyone done with buf0
    if (kt + 2 < S_ / 64) stageKV(kt + 2, (char*)sK0, (char*)sV0);
    tile((char*)sK1, (char*)sV1);
    __syncthreads();                 // buf0 ready; everyone done with buf1
  }

  float inv[4];
#pragma unroll
  for (int j = 0; j < 4; ++j) inv[j] = 1.f / lrow[j];
#pragma unroll
  for (int n2 = 0; n2 < 4; ++n2) {
#pragma unroll
    for (int j = 0; j < 4; ++j) {
      const size_t row = rowQ + w * 16 + (l >> 4) * 4 + j;
      const int col = col0 + n2 * 16 + (l & 15);
      float x = o[n2][j] * inv[j];
      if (addend != nullptr) x += bf2f(addend[row * D_ + col]);
      O[row * D_ + col] = f2bf(x);
    }
  }
}

// ---------------------------------------------------------------------------
// Host-side orchestration
// ---------------------------------------------------------------------------
extern "C" void kernel_launch(void* const* d_in, const int* in_sizes, int n_in,
                              void* d_out, int out_size, void* d_ws, size_t ws_size,
                              hipStream_t stream) {
  const float* gf = (const float*)d_in[0];
  const float* lf = (const float*)d_in[1];
  const float* tf = (const float*)d_in[2];
  const float* ge_w  = (const float*)d_in[3],  *ge_b  = (const float*)d_in[4];
  const float* le1_w = (const float*)d_in[5],  *le1_b = (const float*)d_in[6];
  const float* le2_w = (const float*)d_in[7],  *le2_b = (const float*)d_in[8];
  const float* qg_w  = (const float*)d_in[9],  *qg_b  = (const float*)d_in[10];
  const float* kg_w  = (const float*)d_in[11], *kg_b  = (const float*)d_in[12];
  const float* vg_w  = (const float*)d_in[13], *vg_b  = (const float*)d_in[14];
  const float* qp_w  = (const float*)d_in[15], *qp_b  = (const float*)d_in[16];
  const float* kp_w  = (const float*)d_in[17], *kp_b  = (const float*)d_in[18];
  const float* vp_w  = (const float*)d_in[19], *vp_b  = (const float*)d_in[20];
  const float* dense_w = (const float*)d_in[21], *dense_b = (const float*)d_in[22];
  const float* ml_w  = (const float*)d_in[23], *ml_b  = (const float*)d_in[24];
  const float* fc1_w = (const float*)d_in[25], *fc1_b = (const float*)d_in[26];
  const float* fc2_w = (const float*)d_in[27], *fc2_b = (const float*)d_in[28];

  float* out = (float*)d_out;

  char* p = (char*)d_ws;
  auto take = [&](size_t bytes) { char* r = p; p += (bytes + 255) & ~(size_t)255; return r; };
  const size_t WD  = (size_t)D_ * D_;
  const size_t WF  = (size_t)DFF_ * D_;
  const size_t ACT = (size_t)M_ * D_;
  const size_t HB  = (size_t)M_ * DFF_;

  // bf16 weights (10)
  unsigned short* wqg    = (unsigned short*)take(WD * 2);
  unsigned short* wkg    = (unsigned short*)take(WD * 2);
  unsigned short* wvg    = (unsigned short*)take(WD * 2);
  unsigned short* wqp    = (unsigned short*)take(WD * 2);
  unsigned short* wkp    = (unsigned short*)take(WD * 2);
  unsigned short* wvp    = (unsigned short*)take(WD * 2);
  unsigned short* wdense = (unsigned short*)take(WD * 2);
  unsigned short* wml    = (unsigned short*)take(WD * 2);
  unsigned short* wfc1   = (unsigned short*)take(WF * 2);
  unsigned short* wfc2   = (unsigned short*)take(WF * 2);
  // transposed embedding weights (bf16)
  unsigned short* geT    = (unsigned short*)take(WD * 2);
  unsigned short* le1T   = (unsigned short*)take(WD * 2);
  unsigned short* le2T   = (unsigned short*)take(WD * 2);
  // composed projection weights (bf16) + composed biases (f32)
  unsigned short* cWqg   = (unsigned short*)take(WD * 2);
  unsigned short* cWkg   = (unsigned short*)take(WD * 2);
  unsigned short* cWvg   = (unsigned short*)take(WD * 2);
  unsigned short* cWqp   = (unsigned short*)take(WD * 2);
  float* cbqg = (float*)take(D_ * 4);
  float* cbkg = (float*)take(D_ * 4);
  float* cbvg = (float*)take(D_ * 4);
  float* cbqp = (float*)take(D_ * 4);
  // bf16 activations
  unsigned short* gfb    = (unsigned short*)take(ACT * 2);
  unsigned short* lfb    = (unsigned short*)take(ACT * 2);
  unsigned short* tfb    = (unsigned short*)take(ACT * 2);
  unsigned short* qgb    = (unsigned short*)take(ACT * 2);
  unsigned short* kgb    = (unsigned short*)take(ACT * 2);
  unsigned short* vgb    = (unsigned short*)take(ACT * 2);
  unsigned short* qpb    = (unsigned short*)take(ACT * 2);
  unsigned short* kpb    = (unsigned short*)take(ACT * 2);
  unsigned short* vpb    = (unsigned short*)take(ACT * 2);
  unsigned short* ub     = (unsigned short*)take(ACT * 2);
  unsigned short* lastb  = (unsigned short*)take(ACT * 2);
  unsigned short* out1   = (unsigned short*)take(ACT * 2);
  unsigned short* hbuf   = (unsigned short*)take(HB * 2);
  unsigned short* out2   = (unsigned short*)take(ACT * 2);

  unsigned short* vt1 = gfb;   // dead after s2
  unsigned short* vtu = lfb;   // dead after s2

  // -------- conversions: 10 weights + 3 inputs --------
  CvtB cb;
  const float* srcs[13] = {qg_w, kg_w, vg_w, qp_w, kp_w, vp_w,
                           dense_w, ml_w, fc1_w, fc2_w, gf, lf, tf};
  unsigned short* dsts[13] = {wqg, wkg, wvg, wqp, wkp, wvp,
                              wdense, wml, wfc1, wfc2, gfb, lfb, tfb};
  const int lens[13] = {(int)WD,(int)WD,(int)WD,(int)WD,(int)WD,(int)WD,
                        (int)WD,(int)WD,(int)WF,(int)WF,(int)ACT,(int)ACT,(int)ACT};
  for (int i = 0; i < 13; ++i) { cb.s[i] = srcs[i]; cb.d[i] = dsts[i]; cb.n[i] = lens[i]; }
  hipLaunchKernelGGL(cvt_k, dim3(512, 13), dim3(256), 0, stream, cb);

  const dim3 blk(256);
  auto mkb = [](std::initializer_list<const unsigned short*> As,
                std::initializer_list<const unsigned short*> Ws,
                std::initializer_list<const float*> Bs,
                std::initializer_list<void*> Ys) {
    GemmB g{};
    int i = 0;
    auto a = As.begin(); auto w = Ws.begin(); auto b = Bs.begin(); auto y = Ys.begin();
    for (; a != As.end(); ++a, ++w, ++b, ++y, ++i) { g.A[i] = *a; g.W[i] = *w; g.bias[i] = *b; g.Y[i] = *y; }
    return g;
  };

  // -------- embedding fold: qg = gf@(Wq We)^T + (Wq be + bq), etc. --------
  WtB wt;
  wt.s[0] = ge_w; wt.s[1] = le1_w; wt.s[2] = le2_w;
  wt.d[0] = geT;  wt.d[1] = le1T;  wt.d[2] = le2T;
  hipLaunchKernelGGL(wtrans_k, dim3(32, 16, 3), blk, 0, stream, wt);

  BcB bc;
  bc.w[0] = qg_w; bc.eb[0] = ge_b;  bc.pb[0] = qg_b; bc.o[0] = cbqg;
  bc.w[1] = kg_w; bc.eb[1] = le2_b; bc.pb[1] = kg_b; bc.o[1] = cbkg;
  bc.w[2] = vg_w; bc.eb[2] = le2_b; bc.pb[2] = vg_b; bc.o[2] = cbvg;
  bc.w[3] = qp_w; bc.eb[3] = le1_b; bc.pb[3] = qp_b; bc.o[3] = cbqp;
  hipLaunchKernelGGL(bcomp_k, dim3(16, 4), blk, 0, stream, bc);

  GemmB wc = mkb({wqg, wkg, wvg, wqp}, {geT, le2T, le2T, le1T},
                 {ge_b, ge_b, ge_b, ge_b},   // unused (NB=1)
                 {cWqg, cWkg, cWvg, cWqp});
  hipLaunchKernelGGL((mgemm<0,0,1>), dim3(D_/128, D_/128, 4), blk, 0, stream, wc, D_, D_, D_);

  // -------- QKV projections directly from inputs (stage-1 folded away) -----
  GemmB s2 = mkb({gfb, lfb, lfb, lfb, tfb, tfb},
                 {cWqg, cWkg, cWvg, cWqp, wkp, wvp},
                 {cbqg, cbkg, cbvg, cbqp, kp_b, vp_b},
                 {qgb, kgb, vgb, qpb, kpb, vpb});
  hipLaunchKernelGGL((mgemm<0,0,0>), dim3(D_/128, M_/128, 6), blk, 0, stream, s2, M_, D_, D_);

  // attention (bridge collapsed by associativity):
  //   u    = vg + softmax(qp kp^T / 8) @ vp
  //   last = softmax(qg kg^T / 8) @ u
  hipLaunchKernelGGL(vtrans_k, dim3(32, 64), blk, 0, stream, vpb, vt1);
  hipLaunchKernelGGL(attn_mfma_k, dim3(16, 64), blk, 0, stream, qpb, kpb, vt1, vgb, ub);
  hipLaunchKernelGGL(vtrans_k, dim3(32, 64), blk, 0, stream, ub, vtu);
  hipLaunchKernelGGL(attn_mfma_k, dim3(16, 64), blk, 0, stream, qgb, kgb, vtu,
                     (const unsigned short*)nullptr, lastb);

  // tail: dense -> fc1(GELU) -> fc2 -> ml
  GemmB gd = mkb({lastb}, {wdense}, {dense_b}, {out1});
  hipLaunchKernelGGL((mgemm<0,0,0>), dim3(D_/128, M_/128, 1), blk, 0, stream, gd, M_, D_, D_);
  GemmB g1 = mkb({out1}, {wfc1}, {fc1_b}, {hbuf});
  hipLaunchKernelGGL((mgemm<1,0,0>), dim3(DFF_/128, M_/128, 1), blk, 0, stream, g1, M_, DFF_, D_);
  GemmB g2 = mkb({hbuf}, {wfc2}, {fc2_b}, {out2});
  hipLaunchKernelGGL((mgemm<0,0,0>), dim3(D_/128, M_/128, 1), blk, 0, stream, g2, M_, D_, DFF_);
  GemmB gm = mkb({out2}, {wml}, {ml_b}, {out});
  hipLaunchKernelGGL((mgemm<0,1,0>), dim3(D_/128, M_/128, 1), blk, 0, stream, gm, M_, D_, D_);
}